// Round 11
// baseline (724.119 us; speedup 1.0000x reference)
//
#include <hip/hip_runtime.h>
#include <hip/hip_fp16.h>

#define NF 35
#define HS 36        // h row stride (fp32)
#define TMAT 2450    // 70*35 per theta matrix
// z|r path: 10 SoA slabs, each [n] x 36 halves (72B/row):
//   0 zg, 1 rg, 2 az1, 3 ar1, 4 az2, 5 ar2, 6 bz1, 7 br1, 8 bz2, 9 br2
// c path: 5 SoA slabs: 0 cg, 1 cf1, 2 cf2, 3 cb1, 4 cb2
#define ZCOLS 384
#define ZUSED 360
#define CCOLS 192
#define CUSED 180

// ================= CSR build =================

__global__ void degree2_k(const int* __restrict__ src, const int* __restrict__ dst,
                          unsigned int* __restrict__ cntF2, unsigned int* __restrict__ cntB2,
                          int* __restrict__ rankF, int* __restrict__ rankB, int E) {
    int e = blockIdx.x * blockDim.x + threadIdx.x;
    if (e < E) {
        int d = dst[e], s = src[e];
        int shd = (d & 1) * 16, shs = (s & 1) * 16;
        unsigned int o1 = atomicAdd(&cntF2[d >> 1], 1u << shd);
        rankF[e] = (int)((o1 >> shd) & 0xFFFFu);
        unsigned int o2 = atomicAdd(&cntB2[s >> 1], 1u << shs);
        rankB[e] = (int)((o2 >> shs) & 0xFFFFu);
    }
}

__global__ __launch_bounds__(1024) void scan2_k(const unsigned int* __restrict__ cntF2,
                                                const unsigned int* __restrict__ cntB2,
                                                int* __restrict__ rowF,
                                                int* __restrict__ rowB, int n) {
    const unsigned int* cnt = blockIdx.x ? cntB2 : cntF2;
    int* row = blockIdx.x ? rowB : rowF;
    __shared__ int wsum[16];
    __shared__ int carry_s;
    int lane = threadIdx.x & 63, wid = threadIdx.x >> 6;
    if (threadIdx.x == 0) carry_s = 0;
    __syncthreads();
    for (int base = 0; base < n; base += 1024) {
        int i = base + threadIdx.x;
        int v = 0;
        if (i < n) v = (int)((cnt[i >> 1] >> ((i & 1) * 16)) & 0xFFFFu);
        int s = v;
        for (int off = 1; off < 64; off <<= 1) {
            int t = __shfl_up(s, off, 64);
            if (lane >= off) s += t;
        }
        if (lane == 63) wsum[wid] = s;
        __syncthreads();
        if (wid == 0) {
            int t = (lane < 16) ? wsum[lane] : 0;
            int ss = t;
            for (int off = 1; off < 16; off <<= 1) {
                int u = __shfl_up(ss, off, 64);
                if (lane >= off) ss += u;
            }
            if (lane < 16) wsum[lane] = ss - t;
        }
        __syncthreads();
        if (i < n) row[i] = carry_s + wsum[wid] + s - v;
        __syncthreads();
        if (threadIdx.x == 1023) carry_s += wsum[15] + s;
        __syncthreads();
    }
    if (threadIdx.x == 0) row[n] = carry_s;
}

__global__ void scatter2_k(const int* __restrict__ src, const int* __restrict__ dst,
                           const float* __restrict__ w,
                           const int* __restrict__ rankF, const int* __restrict__ rankB,
                           const int* __restrict__ rowF, const int* __restrict__ rowB,
                           int2* __restrict__ pairF, int2* __restrict__ pairB, int E) {
    int e = blockIdx.x * blockDim.x + threadIdx.x;
    if (e < E) {
        int s = src[e], d = dst[e];
        int wb = __float_as_int(w[e]);
        pairF[rowF[d] + rankF[e]] = make_int2(s, wb);
        pairB[rowB[s] + rankB[e]] = make_int2(d, wb);
    }
}

__global__ void segdeg_k(const int* __restrict__ rowF, const int* __restrict__ rowB,
                         const int2* __restrict__ pairF, const int2* __restrict__ pairB,
                         float* __restrict__ deg_in, float* __restrict__ deg_out, int n) {
    int i = blockIdx.x * blockDim.x + threadIdx.x;
    if (i >= n) return;
    float a = 0.f;
    for (int p = rowF[i]; p < rowF[i + 1]; ++p) a += __int_as_float(pairF[p].y);
    deg_in[i] = a;
    float b = 0.f;
    for (int p = rowB[i]; p < rowB[i + 1]; ++p) b += __int_as_float(pairB[p].y);
    deg_out[i] = b;
}

__global__ void norm_k(const int* __restrict__ src, const int* __restrict__ dst,
                       const float* __restrict__ w, const float* __restrict__ deg_out,
                       const float* __restrict__ deg_in,
                       const int2* __restrict__ pairF, const int2* __restrict__ pairB,
                       unsigned int* __restrict__ pFp, unsigned int* __restrict__ pBp,
                       float* __restrict__ wf, float* __restrict__ wb, int E) {
    int e = blockIdx.x * blockDim.x + threadIdx.x;
    if (e >= E) return;
    float ww = w[e];
    float a = deg_out[src[e]];
    float b = deg_in[dst[e]];
    wf[e] = ww / (a > 0.f ? a : 1.f);
    wb[e] = ww / (b > 0.f ? b : 1.f);
    int2 pa = pairF[e];
    float da = deg_out[pa.x];
    float wa = __int_as_float(pa.y) / (da > 0.f ? da : 1.f);
    pFp[e] = (unsigned int)pa.x |
             ((unsigned int)__half_as_ushort(__float2half_rn(wa)) << 16);
    int2 pb = pairB[e];
    float db = deg_in[pb.x];
    float wbv = __int_as_float(pb.y) / (db > 0.f ? db : 1.f);
    pBp[e] = (unsigned int)pb.x |
             ((unsigned int)__half_as_ushort(__float2half_rn(wbv)) << 16);
}

// ================= weight packing =================

__global__ void pack_k(const float* __restrict__ tz, const float* __restrict__ tr_,
                       const float* __restrict__ tc, const float* __restrict__ bz,
                       const float* __restrict__ br, const float* __restrict__ bc,
                       float* __restrict__ PZ, float* __restrict__ PC) {
    int i = blockIdx.x * 256 + threadIdx.x;
    const int tot1 = 71 * ZCOLS;
    if (i < tot1) {
        int r = i / ZCOLS, j = i - r * ZCOLS;
        int s = j / 36, jl = j - s * 36;
        float v = 0.f;
        if (s < 10 && jl < 35) {
            int zr = s & 1;
            const float* th = zr ? tr_ : tz;
            int grp = s >> 1;
            if (r < 70) {
                if (grp == 0) v = th[r * 35 + jl] + th[3 * TMAT + r * 35 + jl];
                else {
                    int off = (grp == 1) ? 1 : (grp == 2) ? 2 : (grp == 3) ? 4 : 5;
                    v = th[off * TMAT + r * 35 + jl];
                }
            } else if (grp == 0) {
                v = zr ? br[jl] : bz[jl];
            }
        }
        PZ[i] = v;
    } else {
        int i2 = i - tot1;
        if (i2 < 71 * CCOLS) {
            int r = i2 / CCOLS, j = i2 - r * CCOLS;
            int s = j / 36, jl = j - s * 36;
            float v = 0.f;
            if (s < 5 && jl < 35) {
                if (r < 70) {
                    if (s == 0) v = tc[r * 35 + jl] + tc[3 * TMAT + r * 35 + jl];
                    else {
                        int off = (s == 1) ? 1 : (s == 2) ? 2 : (s == 3) ? 4 : 5;
                        v = tc[off * TMAT + r * 35 + jl];
                    }
                } else if (s == 0) v = bc[jl];
            }
            PC[i2] = v;
        }
    }
}

// ================= half helpers =================

__device__ __forceinline__ uint2 pack4h(float4 a) {
    __half2 lo = __floats2half2_rn(a.x, a.y);
    __half2 hi = __floats2half2_rn(a.z, a.w);
    uint2 r;
    r.x = *(unsigned int*)&lo;
    r.y = *(unsigned int*)&hi;
    return r;
}

__device__ __forceinline__ void fma2h(float* a, unsigned int v, float w) {
    float2 f = __half22float2(*(__half2*)&v);
    a[0] += w * f.x;
    a[1] += w * f.y;
}

__device__ __forceinline__ void fma4u2(float* a, uint2 v, float w) {
    fma2h(a, v.x, w);
    fma2h(a + 2, v.y, w);
}

__device__ __forceinline__ void ld4h(float* a, const char* p) {
    uint2 v = *(const uint2*)p;
    a[0] = 0.f; a[1] = 0.f; a[2] = 0.f; a[3] = 0.f;
    fma4u2(a, v, 1.f);
}

__device__ __forceinline__ void st4h(const float* a, char* p) {
    *(uint2*)p = pack4h(make_float4(a[0], a[1], a[2], a[3]));
}

__device__ __forceinline__ float hw(unsigned int e) {
    return __half2float(__ushort_as_half((unsigned short)(e >> 16)));
}

// single-slab 8B gather (4-edge pipeline)
__device__ __forceinline__ void gath8(float* acc, const char* slab, int off,
                                      const int* __restrict__ rp,
                                      const unsigned int* __restrict__ pp, int row) {
    int p = rp[row], p1 = rp[row + 1];
    for (; p + 3 < p1; p += 4) {
        unsigned int e0 = pp[p], e1 = pp[p + 1], e2 = pp[p + 2], e3 = pp[p + 3];
        uint2 v0 = *(const uint2*)(slab + (size_t)(e0 & 0xFFFFu) * 72 + off);
        uint2 v1 = *(const uint2*)(slab + (size_t)(e1 & 0xFFFFu) * 72 + off);
        uint2 v2 = *(const uint2*)(slab + (size_t)(e2 & 0xFFFFu) * 72 + off);
        uint2 v3 = *(const uint2*)(slab + (size_t)(e3 & 0xFFFFu) * 72 + off);
        fma4u2(acc, v0, hw(e0));
        fma4u2(acc, v1, hw(e1));
        fma4u2(acc, v2, hw(e2));
        fma4u2(acc, v3, hw(e3));
    }
    for (; p < p1; ++p) {
        unsigned int e0 = pp[p];
        uint2 v0 = *(const uint2*)(slab + (size_t)(e0 & 0xFFFFu) * 72 + off);
        fma4u2(acc, v0, hw(e0));
    }
}

// dual-slab 8B gather: one pair word feeds both slabs (8 loads in flight)
__device__ __forceinline__ void gath8x2(float* a1, float* a2, const char* s1b,
                                        const char* s2b, int off,
                                        const int* __restrict__ rp,
                                        const unsigned int* __restrict__ pp, int row) {
    int p = rp[row], p1 = rp[row + 1];
    for (; p + 3 < p1; p += 4) {
        unsigned int e0 = pp[p], e1 = pp[p + 1], e2 = pp[p + 2], e3 = pp[p + 3];
        size_t b0 = (size_t)(e0 & 0xFFFFu) * 72 + off;
        size_t b1 = (size_t)(e1 & 0xFFFFu) * 72 + off;
        size_t b2 = (size_t)(e2 & 0xFFFFu) * 72 + off;
        size_t b3 = (size_t)(e3 & 0xFFFFu) * 72 + off;
        uint2 x0 = *(const uint2*)(s1b + b0), y0 = *(const uint2*)(s2b + b0);
        uint2 x1 = *(const uint2*)(s1b + b1), y1 = *(const uint2*)(s2b + b1);
        uint2 x2 = *(const uint2*)(s1b + b2), y2 = *(const uint2*)(s2b + b2);
        uint2 x3 = *(const uint2*)(s1b + b3), y3 = *(const uint2*)(s2b + b3);
        float w0 = hw(e0), w1 = hw(e1), w2 = hw(e2), w3 = hw(e3);
        fma4u2(a1, x0, w0); fma4u2(a2, y0, w0);
        fma4u2(a1, x1, w1); fma4u2(a2, y1, w1);
        fma4u2(a1, x2, w2); fma4u2(a2, y2, w2);
        fma4u2(a1, x3, w3); fma4u2(a2, y3, w3);
    }
    for (; p < p1; ++p) {
        unsigned int e0 = pp[p];
        size_t b0 = (size_t)(e0 & 0xFFFFu) * 72 + off;
        float w0 = hw(e0);
        fma4u2(a1, *(const uint2*)(s1b + b0), w0);
        fma4u2(a2, *(const uint2*)(s2b + b0), w0);
    }
}

// ================= GEMM tile body: 64 rows (LDS) x 64 cols -> SoA slabs =================

template <int WCOLS, int USED>
__device__ __forceinline__ void gemm_tile(const float* sxr, const float* __restrict__ W,
                                          char* OUT, size_t slb, int grow, bool valid,
                                          int j0, int kdim) {
    if (j0 >= USED) return;
    const float4* bw = (const float4*)(W + (size_t)70 * WCOLS + j0);
    float4 a0 = bw[0], a1 = bw[1], a2 = bw[2], a3 = bw[3];
    for (int c = 0; c < kdim; ++c) {
        float v = sxr[c];
        const float4* wr = (const float4*)(W + (size_t)c * WCOLS + j0);
        float4 w0 = wr[0], w1 = wr[1], w2 = wr[2], w3 = wr[3];
        a0.x += v * w0.x; a0.y += v * w0.y; a0.z += v * w0.z; a0.w += v * w0.w;
        a1.x += v * w1.x; a1.y += v * w1.y; a1.z += v * w1.z; a1.w += v * w1.w;
        a2.x += v * w2.x; a2.y += v * w2.y; a2.z += v * w2.z; a2.w += v * w2.w;
        a3.x += v * w3.x; a3.y += v * w3.y; a3.z += v * w3.z; a3.w += v * w3.w;
    }
    if (valid) {
        float4 as[4] = {a0, a1, a2, a3};
#pragma unroll
        for (int g = 0; g < 4; ++g) {
            int jc = j0 + 4 * g;
            if (jc >= USED) break;
            int s = jc / 36, off = jc - s * 36;
            *(uint2*)(OUT + (size_t)s * slb + (size_t)grow * 72 + off * 2) = pack4h(as[g]);
        }
    }
}

// ================= mm z|r path: zS = (x|h) @ PZ ; j-tile = blockIdx.y =================

template <int H0>
__global__ __launch_bounds__(256) void mm_z_k(const float* __restrict__ x,
                                              const float* __restrict__ h,
                                              const float* __restrict__ W,
                                              char* __restrict__ zS, int n) {
    __shared__ float sx[64 * 73];
    int row0 = blockIdx.x * 64;
    for (int t = threadIdx.x; t < 64 * 35; t += 256) {
        int rl = t / 35, c = t - rl * 35;
        int grow = row0 + rl;
        sx[rl * 73 + c] = (grow < n) ? x[(size_t)grow * 35 + c] : 0.f;
    }
    if (!H0) {
        for (int t = threadIdx.x; t < 64 * 35; t += 256) {
            int rl = t / 35, c = t - rl * 35;
            int grow = row0 + rl;
            sx[rl * 73 + 35 + c] = (grow < n) ? h[(size_t)grow * HS + c] : 0.f;
        }
    }
    __syncthreads();
    int lane = threadIdx.x & 63;
    int wid = threadIdx.x >> 6;
    int grow = row0 + lane;
    int j0 = __builtin_amdgcn_readfirstlane(blockIdx.y * 64 + wid * 16);
    gemm_tile<ZCOLS, ZUSED>(&sx[lane * 73], W, zS, (size_t)n * 72, grow, grow < n,
                            j0, H0 ? 35 : 70);
}

// ================= mm c path: cS = (x | r*h) @ PC ; j-tile = blockIdx.y =================

__global__ __launch_bounds__(256) void mmc_k(const float* __restrict__ x,
                                             const float* __restrict__ h,
                                             const char* __restrict__ zS,
                                             const float* __restrict__ W,
                                             char* __restrict__ cS, int n) {
    __shared__ float sx[64 * 73];
    size_t slb = (size_t)n * 72;
    int row0 = blockIdx.x * 64;
    for (int t = threadIdx.x; t < 64 * 35; t += 256) {
        int rl = t / 35, c = t - rl * 35;
        int grow = row0 + rl;
        sx[rl * 73 + c] = (grow < n) ? x[(size_t)grow * 35 + c] : 0.f;
    }
    for (int t = threadIdx.x; t < 64 * 35; t += 256) {
        int rl = t / 35, c = t - rl * 35;
        int grow = row0 + rl;
        float v = 0.f;
        if (grow < n) {
            float r = __half2float(*(const __half*)(zS + slb + (size_t)grow * 72 + 2 * c));
            v = r * h[(size_t)grow * HS + c];
        }
        sx[rl * 73 + 35 + c] = v;
    }
    __syncthreads();
    int lane = threadIdx.x & 63;
    int wid = threadIdx.x >> 6;
    int grow = row0 + lane;
    int j0 = __builtin_amdgcn_readfirstlane(blockIdx.y * 64 + wid * 16);
    gemm_tile<CCOLS, CUSED>(&sx[lane * 73], W, cS, slb, grow, grow < n, j0, 70);
}

// ================= hops: 9 threads/row x 8B, z+r merged =================

// hopAzr: pass y=0: az1+=Tf*az2, ar1+=Tf*ar2 ; y=1: bz1+=Tb*bz2, br1+=Tb*br2
__global__ __launch_bounds__(256) void hopAzr_k(char* __restrict__ zS,
                                                const int* __restrict__ rowF,
                                                const int* __restrict__ rowB,
                                                const unsigned int* __restrict__ pF,
                                                const unsigned int* __restrict__ pB,
                                                int n) {
    int i = blockIdx.x * 256 + threadIdx.x;
    if (i >= n * 9) return;
    size_t slb = (size_t)n * 72;
    int pass = blockIdx.y;
    const int* rp = pass ? rowB : rowF;
    const unsigned int* pp = pass ? pB : pF;
    int dz = pass ? 6 : 2;           // dest z slab
    int row = i / 9, t = i - row * 9;
    int off = 8 * t;
    char* wpz = zS + (size_t)dz * slb + (size_t)row * 72 + off;
    char* wpr = wpz + slb;           // dest r slab = dz+1
    float az[4], ar[4];
    ld4h(az, wpz);
    ld4h(ar, wpr);
    gath8x2(az, ar, zS + (size_t)(dz + 2) * slb, zS + (size_t)(dz + 3) * slb,
            off, rp, pp, row);
    st4h(az, wpz);
    st4h(ar, wpr);
}

// hopBzr: zg=sig(zg+Tf*az1+Tb*bz1); rg=sig(rg+Tf*ar1+Tb*br1)
__global__ __launch_bounds__(256) void hopBzr_k(char* __restrict__ zS,
                                                const int* __restrict__ rowF,
                                                const int* __restrict__ rowB,
                                                const unsigned int* __restrict__ pF,
                                                const unsigned int* __restrict__ pB,
                                                int n) {
    int i = blockIdx.x * 256 + threadIdx.x;
    if (i >= n * 9) return;
    size_t slb = (size_t)n * 72;
    int row = i / 9, t = i - row * 9;
    int off = 8 * t;
    char* wpz = zS + (size_t)row * 72 + off;
    char* wpr = wpz + slb;
    float az[4], ar[4];
    ld4h(az, wpz);
    ld4h(ar, wpr);
    gath8x2(az, ar, zS + 2 * slb, zS + 3 * slb, off, rowF, pF, row);
    gath8x2(az, ar, zS + 6 * slb, zS + 7 * slb, off, rowB, pB, row);
#pragma unroll
    for (int k = 0; k < 4; ++k) {
        az[k] = 1.f / (1.f + expf(-az[k]));
        ar[k] = 1.f / (1.f + expf(-ar[k]));
    }
    st4h(az, wpz);
    st4h(ar, wpr);
}

// hopAc: cf1+=Tf*cf2 then cb1+=Tb*cb2 (one thread both dirs)
__global__ __launch_bounds__(256) void hopAc_k(char* __restrict__ cS,
                                               const int* __restrict__ rowF,
                                               const int* __restrict__ rowB,
                                               const unsigned int* __restrict__ pF,
                                               const unsigned int* __restrict__ pB,
                                               int n) {
    int i = blockIdx.x * 256 + threadIdx.x;
    if (i >= n * 9) return;
    size_t slb = (size_t)n * 72;
    int row = i / 9, t = i - row * 9;
    int off = 8 * t;
    {
        char* wp = cS + slb + (size_t)row * 72 + off;        // cf1
        float acc[4];
        ld4h(acc, wp);
        gath8(acc, cS + 2 * slb, off, rowF, pF, row);        // += Tf*cf2
        st4h(acc, wp);
    }
    {
        char* wp = cS + 3 * slb + (size_t)row * 72 + off;    // cb1
        float acc[4];
        ld4h(acc, wp);
        gath8(acc, cS + 4 * slb, off, rowB, pB, row);        // += Tb*cb2
        st4h(acc, wp);
    }
}

// hopBc + GRU: h = z*h + (1-z)*tanh(cg + Tf*cf1 + Tb*cb1)
__global__ __launch_bounds__(256) void hopBcg_k(const char* __restrict__ cS,
                                                const char* __restrict__ zS,
                                                const int* __restrict__ rowF,
                                                const int* __restrict__ rowB,
                                                const unsigned int* __restrict__ pF,
                                                const unsigned int* __restrict__ pB,
                                                float* __restrict__ h, int n) {
    int i = blockIdx.x * 256 + threadIdx.x;
    if (i >= n * 9) return;
    size_t slb = (size_t)n * 72;
    int row = i / 9, t = i - row * 9;
    int off = 8 * t;
    float acc[4];
    ld4h(acc, cS + (size_t)row * 72 + off);              // cg
    gath8(acc, cS + slb, off, rowF, pF, row);            // + Tf*cf1
    gath8(acc, cS + 3 * slb, off, rowB, pB, row);        // + Tb*cb1
    float zv[4];
    ld4h(zv, zS + (size_t)row * 72 + off);               // z gate
    float* hp = h + (size_t)row * HS + 4 * t;
    float4 h4 = *(float4*)hp;
    float hv[4] = {h4.x, h4.y, h4.z, h4.w};
#pragma unroll
    for (int k = 0; k < 4; ++k) {
        float c = tanhf(acc[k]);
        hv[k] = zv[k] * hv[k] + (1.f - zv[k]) * c;
    }
    *(float4*)hp = make_float4(hv[0], hv[1], hv[2], hv[3]);
}

// ================= final =================

__global__ void final_k(const float* __restrict__ h, const float* __restrict__ Wl,
                        const float* __restrict__ bl, float* __restrict__ out, int n) {
    int i = blockIdx.x * blockDim.x + threadIdx.x;
    if (i < n) {
        float s = bl[0];
        const float* hr = h + (size_t)i * HS;
#pragma unroll
        for (int j = 0; j < NF; j++) s += hr[j] * Wl[j];
        out[i] = fmaxf(s, 0.f);
    }
}

// ================= launch =================

extern "C" void kernel_launch(void* const* d_in, const int* in_sizes, int n_in,
                              void* d_out, int out_size, void* d_ws, size_t ws_size,
                              hipStream_t stream) {
    const float* x   = (const float*)d_in[0];
    const int*   ei  = (const int*)d_in[1];
    const float* w   = (const float*)d_in[2];
    const float* tz  = (const float*)d_in[3];
    const float* bz  = (const float*)d_in[4];
    const float* tr_ = (const float*)d_in[5];
    const float* br  = (const float*)d_in[6];
    const float* tc  = (const float*)d_in[7];
    const float* bc  = (const float*)d_in[8];
    const float* Wl  = (const float*)d_in[9];
    const float* bl  = (const float*)d_in[10];

    const int n = in_sizes[0] / NF;   // 50000 (< 65536: packed 16-bit indices)
    const int E = in_sizes[2];        // 800000
    const int* src = ei;
    const int* dst = ei + E;

    float* out = (float*)d_out;       // [n]
    float* wf = out + n;              // [E]  = A[0]
    float* wb = wf + E;               // [E]  = A[1]

    char* p = (char*)d_ws;
    auto alloc = [&](size_t bytes) {
        char* r = p;
        p += (bytes + 15) & ~(size_t)15;
        return r;
    };
    int2* pairF = (int2*)alloc((size_t)E * 8);
    int2* pairB = (int2*)alloc((size_t)E * 8);
    unsigned int* pFp = (unsigned int*)alloc((size_t)E * 4);
    unsigned int* pBp = (unsigned int*)alloc((size_t)E * 4);
    int* rowF = (int*)alloc((size_t)(n + 1) * 4);
    int* rowB = (int*)alloc((size_t)(n + 1) * 4);
    unsigned int* cntF2 = (unsigned int*)alloc((size_t)((n + 1) / 2 + 4) * 4);
    unsigned int* cntB2 = (unsigned int*)alloc((size_t)((n + 1) / 2 + 4) * 4);
    float* deg_in  = (float*)alloc((size_t)n * 4);
    float* deg_out = (float*)alloc((size_t)n * 4);
    float* h  = (float*)alloc((size_t)n * HS * 4);
    char* zS  = alloc((size_t)n * 72 * 10);   // 10 z|r slabs
    char* cS  = alloc((size_t)n * 72 * 5);    // 5 c slabs
    float* PZ = (float*)alloc((size_t)71 * ZCOLS * 4);
    float* PC = (float*)alloc((size_t)71 * CCOLS * 4);
    // ranks live only during build: alias onto zS (6.4MB << 36MB)
    int* rankF = (int*)zS;
    int* rankB = rankF + E;

    const int gridE = (E + 255) / 256;
    const int gridN = (n + 255) / 256;
    const int g64 = (n + 63) / 64;
    const int g9 = (n * 9 + 255) / 256;
    const size_t cntBytes = ((size_t)((n + 1) / 2 + 4) * 4 + 15) & ~(size_t)15;

    // ---- CSR build ----
    hipMemsetAsync(cntF2, 0, 2 * cntBytes, stream);   // cntF2+cntB2 contiguous
    hipMemsetAsync(h, 0, (size_t)n * HS * sizeof(float), stream);
    degree2_k<<<gridE, 256, 0, stream>>>(src, dst, cntF2, cntB2, rankF, rankB, E);
    scan2_k<<<2, 1024, 0, stream>>>(cntF2, cntB2, rowF, rowB, n);
    scatter2_k<<<gridE, 256, 0, stream>>>(src, dst, w, rankF, rankB, rowF, rowB,
                                          pairF, pairB, E);
    segdeg_k<<<gridN, 256, 0, stream>>>(rowF, rowB, pairF, pairB, deg_in, deg_out, n);
    norm_k<<<gridE, 256, 0, stream>>>(src, dst, w, deg_out, deg_in, pairF, pairB,
                                      pFp, pBp, wf, wb, E);
    pack_k<<<(71 * (ZCOLS + CCOLS) + 255) / 256, 256, 0, stream>>>(tz, tr_, tc,
                                                                   bz, br, bc, PZ, PC);

    for (int cellit = 0; cellit < 2; ++cellit) {
        if (cellit == 0)
            mm_z_k<1><<<dim3(g64, 6), 256, 0, stream>>>(x, h, PZ, zS, n);
        else
            mm_z_k<0><<<dim3(g64, 6), 256, 0, stream>>>(x, h, PZ, zS, n);
        hopAzr_k<<<dim3(g9, 2), 256, 0, stream>>>(zS, rowF, rowB, pFp, pBp, n);
        hopBzr_k<<<g9, 256, 0, stream>>>(zS, rowF, rowB, pFp, pBp, n);
        mmc_k<<<dim3(g64, 3), 256, 0, stream>>>(x, h, zS, PC, cS, n);
        hopAc_k<<<g9, 256, 0, stream>>>(cS, rowF, rowB, pFp, pBp, n);
        hopBcg_k<<<g9, 256, 0, stream>>>(cS, zS, rowF, rowB, pFp, pBp, h, n);
    }

    final_k<<<gridN, 256, 0, stream>>>(h, Wl, bl, out, n);
}

// Round 12
// 619.720 us; speedup vs baseline: 1.1685x; 1.1685x over previous
//
#include <hip/hip_runtime.h>
#include <hip/hip_fp16.h>

#define NF 35
#define HS 36        // h row stride (fp32)
#define TMAT 2450    // 70*35 per theta matrix
// z|r path: 10 SoA slabs, each [n] x 36 halves (72B/row):
//   0 zg, 1 rg, 2 az1, 3 ar1, 4 az2, 5 ar2, 6 bz1, 7 br1, 8 bz2, 9 br2
// c path: 5 SoA slabs: 0 cg, 1 cf1, 2 cf2, 3 cb1, 4 cb2
#define ZCOLS 384
#define ZUSED 360
#define CCOLS 192
#define CUSED 180

// ================= CSR build =================

__global__ void degree2_k(const int* __restrict__ src, const int* __restrict__ dst,
                          unsigned int* __restrict__ cntF2, unsigned int* __restrict__ cntB2,
                          int* __restrict__ rankF, int* __restrict__ rankB, int E) {
    int e = blockIdx.x * blockDim.x + threadIdx.x;
    if (e < E) {
        int d = dst[e], s = src[e];
        int shd = (d & 1) * 16, shs = (s & 1) * 16;
        unsigned int o1 = atomicAdd(&cntF2[d >> 1], 1u << shd);
        rankF[e] = (int)((o1 >> shd) & 0xFFFFu);
        unsigned int o2 = atomicAdd(&cntB2[s >> 1], 1u << shs);
        rankB[e] = (int)((o2 >> shs) & 0xFFFFu);
    }
}

__global__ __launch_bounds__(1024) void scan2_k(const unsigned int* __restrict__ cntF2,
                                                const unsigned int* __restrict__ cntB2,
                                                int* __restrict__ rowF,
                                                int* __restrict__ rowB, int n) {
    const unsigned int* cnt = blockIdx.x ? cntB2 : cntF2;
    int* row = blockIdx.x ? rowB : rowF;
    __shared__ int wsum[16];
    __shared__ int carry_s;
    int lane = threadIdx.x & 63, wid = threadIdx.x >> 6;
    if (threadIdx.x == 0) carry_s = 0;
    __syncthreads();
    for (int base = 0; base < n; base += 1024) {
        int i = base + threadIdx.x;
        int v = 0;
        if (i < n) v = (int)((cnt[i >> 1] >> ((i & 1) * 16)) & 0xFFFFu);
        int s = v;
        for (int off = 1; off < 64; off <<= 1) {
            int t = __shfl_up(s, off, 64);
            if (lane >= off) s += t;
        }
        if (lane == 63) wsum[wid] = s;
        __syncthreads();
        if (wid == 0) {
            int t = (lane < 16) ? wsum[lane] : 0;
            int ss = t;
            for (int off = 1; off < 16; off <<= 1) {
                int u = __shfl_up(ss, off, 64);
                if (lane >= off) ss += u;
            }
            if (lane < 16) wsum[lane] = ss - t;
        }
        __syncthreads();
        if (i < n) row[i] = carry_s + wsum[wid] + s - v;
        __syncthreads();
        if (threadIdx.x == 1023) carry_s += wsum[15] + s;
        __syncthreads();
    }
    if (threadIdx.x == 0) row[n] = carry_s;
}

__global__ void scatter2_k(const int* __restrict__ src, const int* __restrict__ dst,
                           const float* __restrict__ w,
                           const int* __restrict__ rankF, const int* __restrict__ rankB,
                           const int* __restrict__ rowF, const int* __restrict__ rowB,
                           int2* __restrict__ pairF, int2* __restrict__ pairB, int E) {
    int e = blockIdx.x * blockDim.x + threadIdx.x;
    if (e < E) {
        int s = src[e], d = dst[e];
        int wb = __float_as_int(w[e]);
        pairF[rowF[d] + rankF[e]] = make_int2(s, wb);
        pairB[rowB[s] + rankB[e]] = make_int2(d, wb);
    }
}

__global__ void segdeg_k(const int* __restrict__ rowF, const int* __restrict__ rowB,
                         const int2* __restrict__ pairF, const int2* __restrict__ pairB,
                         float* __restrict__ deg_in, float* __restrict__ deg_out, int n) {
    int i = blockIdx.x * blockDim.x + threadIdx.x;
    if (i >= n) return;
    float a = 0.f;
    for (int p = rowF[i]; p < rowF[i + 1]; ++p) a += __int_as_float(pairF[p].y);
    deg_in[i] = a;
    float b = 0.f;
    for (int p = rowB[i]; p < rowB[i + 1]; ++p) b += __int_as_float(pairB[p].y);
    deg_out[i] = b;
}

__global__ void norm_k(const int* __restrict__ src, const int* __restrict__ dst,
                       const float* __restrict__ w, const float* __restrict__ deg_out,
                       const float* __restrict__ deg_in,
                       const int2* __restrict__ pairF, const int2* __restrict__ pairB,
                       unsigned int* __restrict__ pFp, unsigned int* __restrict__ pBp,
                       float* __restrict__ wf, float* __restrict__ wb, int E) {
    int e = blockIdx.x * blockDim.x + threadIdx.x;
    if (e >= E) return;
    float ww = w[e];
    float a = deg_out[src[e]];
    float b = deg_in[dst[e]];
    wf[e] = ww / (a > 0.f ? a : 1.f);
    wb[e] = ww / (b > 0.f ? b : 1.f);
    int2 pa = pairF[e];
    float da = deg_out[pa.x];
    float wa = __int_as_float(pa.y) / (da > 0.f ? da : 1.f);
    pFp[e] = (unsigned int)pa.x |
             ((unsigned int)__half_as_ushort(__float2half_rn(wa)) << 16);
    int2 pb = pairB[e];
    float db = deg_in[pb.x];
    float wbv = __int_as_float(pb.y) / (db > 0.f ? db : 1.f);
    pBp[e] = (unsigned int)pb.x |
             ((unsigned int)__half_as_ushort(__float2half_rn(wbv)) << 16);
}

// ================= weight packing =================

__global__ void pack_k(const float* __restrict__ tz, const float* __restrict__ tr_,
                       const float* __restrict__ tc, const float* __restrict__ bz,
                       const float* __restrict__ br, const float* __restrict__ bc,
                       float* __restrict__ PZ, float* __restrict__ PC) {
    int i = blockIdx.x * 256 + threadIdx.x;
    const int tot1 = 71 * ZCOLS;
    if (i < tot1) {
        int r = i / ZCOLS, j = i - r * ZCOLS;
        int s = j / 36, jl = j - s * 36;
        float v = 0.f;
        if (s < 10 && jl < 35) {
            int zr = s & 1;
            const float* th = zr ? tr_ : tz;
            int grp = s >> 1;
            if (r < 70) {
                if (grp == 0) v = th[r * 35 + jl] + th[3 * TMAT + r * 35 + jl];
                else {
                    int off = (grp == 1) ? 1 : (grp == 2) ? 2 : (grp == 3) ? 4 : 5;
                    v = th[off * TMAT + r * 35 + jl];
                }
            } else if (grp == 0) {
                v = zr ? br[jl] : bz[jl];
            }
        }
        PZ[i] = v;
    } else {
        int i2 = i - tot1;
        if (i2 < 71 * CCOLS) {
            int r = i2 / CCOLS, j = i2 - r * CCOLS;
            int s = j / 36, jl = j - s * 36;
            float v = 0.f;
            if (s < 5 && jl < 35) {
                if (r < 70) {
                    if (s == 0) v = tc[r * 35 + jl] + tc[3 * TMAT + r * 35 + jl];
                    else {
                        int off = (s == 1) ? 1 : (s == 2) ? 2 : (s == 3) ? 4 : 5;
                        v = tc[off * TMAT + r * 35 + jl];
                    }
                } else if (s == 0) v = bc[jl];
            }
            PC[i2] = v;
        }
    }
}

// ================= half helpers =================

__device__ __forceinline__ uint2 pack4h(float4 a) {
    __half2 lo = __floats2half2_rn(a.x, a.y);
    __half2 hi = __floats2half2_rn(a.z, a.w);
    uint2 r;
    r.x = *(unsigned int*)&lo;
    r.y = *(unsigned int*)&hi;
    return r;
}

__device__ __forceinline__ void fma2h(float* a, unsigned int v, float w) {
    float2 f = __half22float2(*(__half2*)&v);
    a[0] += w * f.x;
    a[1] += w * f.y;
}

__device__ __forceinline__ void fma4u2(float* a, uint2 v, float w) {
    fma2h(a, v.x, w);
    fma2h(a + 2, v.y, w);
}

__device__ __forceinline__ void ld4h(float* a, const char* p) {
    uint2 v = *(const uint2*)p;
    a[0] = 0.f; a[1] = 0.f; a[2] = 0.f; a[3] = 0.f;
    fma4u2(a, v, 1.f);
}

__device__ __forceinline__ void st4h(const float* a, char* p) {
    *(uint2*)p = pack4h(make_float4(a[0], a[1], a[2], a[3]));
}

__device__ __forceinline__ float hw(unsigned int e) {
    return __half2float(__ushort_as_half((unsigned short)(e >> 16)));
}

// gather-accumulate one 8B chunk from a 72B-row slab; 4-edge pipeline
__device__ __forceinline__ void gath8(float* acc, const char* slab, int off,
                                      const int* __restrict__ rp,
                                      const unsigned int* __restrict__ pp, int row) {
    int p = rp[row], p1 = rp[row + 1];
    for (; p + 3 < p1; p += 4) {
        unsigned int e0 = pp[p], e1 = pp[p + 1], e2 = pp[p + 2], e3 = pp[p + 3];
        uint2 v0 = *(const uint2*)(slab + (size_t)(e0 & 0xFFFFu) * 72 + off);
        uint2 v1 = *(const uint2*)(slab + (size_t)(e1 & 0xFFFFu) * 72 + off);
        uint2 v2 = *(const uint2*)(slab + (size_t)(e2 & 0xFFFFu) * 72 + off);
        uint2 v3 = *(const uint2*)(slab + (size_t)(e3 & 0xFFFFu) * 72 + off);
        fma4u2(acc, v0, hw(e0));
        fma4u2(acc, v1, hw(e1));
        fma4u2(acc, v2, hw(e2));
        fma4u2(acc, v3, hw(e3));
    }
    for (; p < p1; ++p) {
        unsigned int e0 = pp[p];
        uint2 v0 = *(const uint2*)(slab + (size_t)(e0 & 0xFFFFu) * 72 + off);
        fma4u2(acc, v0, hw(e0));
    }
}

// ================= GEMM body: 64 rows (LDS) x WCOLS -> SoA slabs (full width per block) ====
// 8 waves; wave covers j0 = jt*128 + wid*16.

template <int WCOLS, int USED>
__device__ __forceinline__ void gemm_store8(const float* sxr, const float* __restrict__ W,
                                            char* OUT, size_t slb, int grow, bool valid,
                                            int wid, int kdim) {
#pragma unroll
    for (int jt = 0; jt < (WCOLS + 127) / 128; ++jt) {
        int j0 = __builtin_amdgcn_readfirstlane(jt * 128 + wid * 16);
        if (j0 >= USED) continue;
        const float4* bw = (const float4*)(W + (size_t)70 * WCOLS + j0);
        float4 a0 = bw[0], a1 = bw[1], a2 = bw[2], a3 = bw[3];
        for (int c = 0; c < kdim; ++c) {
            float v = sxr[c];
            const float4* wr = (const float4*)(W + (size_t)c * WCOLS + j0);
            float4 w0 = wr[0], w1 = wr[1], w2 = wr[2], w3 = wr[3];
            a0.x += v * w0.x; a0.y += v * w0.y; a0.z += v * w0.z; a0.w += v * w0.w;
            a1.x += v * w1.x; a1.y += v * w1.y; a1.z += v * w1.z; a1.w += v * w1.w;
            a2.x += v * w2.x; a2.y += v * w2.y; a2.z += v * w2.z; a2.w += v * w2.w;
            a3.x += v * w3.x; a3.y += v * w3.y; a3.z += v * w3.z; a3.w += v * w3.w;
        }
        if (valid) {
            float4 as[4] = {a0, a1, a2, a3};
#pragma unroll
            for (int g = 0; g < 4; ++g) {
                int jc = j0 + 4 * g;
                if (jc >= USED) break;
                int s = jc / 36, off = jc - s * 36;
                *(uint2*)(OUT + (size_t)s * slb + (size_t)grow * 72 + off * 2) =
                    pack4h(as[g]);
            }
        }
    }
}

// ================= mm z|r path: zS = (x|h) @ PZ  (H0=1: h==0, K=35) =================

template <int H0>
__global__ __launch_bounds__(512) void mm_z_k(const float* __restrict__ x,
                                              const float* __restrict__ h,
                                              const float* __restrict__ W,
                                              char* __restrict__ zS, int n) {
    __shared__ float sx[64 * 73];
    int row0 = blockIdx.x * 64;
    for (int t = threadIdx.x; t < 64 * 35; t += 512) {
        int rl = t / 35, c = t - rl * 35;
        int grow = row0 + rl;
        sx[rl * 73 + c] = (grow < n) ? x[(size_t)grow * 35 + c] : 0.f;
    }
    if (!H0) {
        for (int t = threadIdx.x; t < 64 * 35; t += 512) {
            int rl = t / 35, c = t - rl * 35;
            int grow = row0 + rl;
            sx[rl * 73 + 35 + c] = (grow < n) ? h[(size_t)grow * HS + c] : 0.f;
        }
    }
    __syncthreads();
    int lane = threadIdx.x & 63;
    int wid = threadIdx.x >> 6;
    int grow = row0 + lane;
    gemm_store8<ZCOLS, ZUSED>(&sx[lane * 73], W, zS, (size_t)n * 72, grow, grow < n,
                              wid, H0 ? 35 : 70);
}

// ================= mm c path: cS = (x | r*h) @ PC =================

__global__ __launch_bounds__(512) void mmc_k(const float* __restrict__ x,
                                             const float* __restrict__ h,
                                             const char* __restrict__ zS,
                                             const float* __restrict__ W,
                                             char* __restrict__ cS, int n) {
    __shared__ float sx[64 * 73];
    size_t slb = (size_t)n * 72;
    int row0 = blockIdx.x * 64;
    for (int t = threadIdx.x; t < 64 * 35; t += 512) {
        int rl = t / 35, c = t - rl * 35;
        int grow = row0 + rl;
        sx[rl * 73 + c] = (grow < n) ? x[(size_t)grow * 35 + c] : 0.f;
    }
    for (int t = threadIdx.x; t < 64 * 35; t += 512) {
        int rl = t / 35, c = t - rl * 35;
        int grow = row0 + rl;
        float v = 0.f;
        if (grow < n) {
            float r = __half2float(*(const __half*)(zS + slb + (size_t)grow * 72 + 2 * c));
            v = r * h[(size_t)grow * HS + c];
        }
        sx[rl * 73 + 35 + c] = v;
    }
    __syncthreads();
    int lane = threadIdx.x & 63;
    int wid = threadIdx.x >> 6;
    int grow = row0 + lane;
    gemm_store8<CCOLS, CUSED>(&sx[lane * 73], W, cS, slb, grow, grow < n, wid, 70);
}

// ================= hops: 9 threads/row x 8B; passes split over blockIdx.y =================

// hopAz: pass y: {az1+=Tf*az2, ar1+=Tf*ar2, bz1+=Tb*bz2, br1+=Tb*br2}
__global__ __launch_bounds__(256) void hopAz_k(char* __restrict__ zS,
                                               const int* __restrict__ rowF,
                                               const int* __restrict__ rowB,
                                               const unsigned int* __restrict__ pF,
                                               const unsigned int* __restrict__ pB,
                                               int n) {
    int i = blockIdx.x * 256 + threadIdx.x;
    if (i >= n * 9) return;
    size_t slb = (size_t)n * 72;
    int pass = blockIdx.y;
    const int* rp = (pass < 2) ? rowF : rowB;
    const unsigned int* pp = (pass < 2) ? pF : pB;
    int dstS = (pass == 0) ? 2 : (pass == 1) ? 3 : (pass == 2) ? 6 : 7;
    int srcS = dstS + 2;
    int row = i / 9, t = i - row * 9;
    int off = 8 * t;
    char* wp = zS + (size_t)dstS * slb + (size_t)row * 72 + off;
    float acc[4];
    ld4h(acc, wp);
    gath8(acc, zS + (size_t)srcS * slb, off, rp, pp, row);
    st4h(acc, wp);
}

// hopBz: pass y in {0:zg, 1:rg}: g = sigmoid(g + Tf*a?1 + Tb*b?1)
__global__ __launch_bounds__(256) void hopBz_k(char* __restrict__ zS,
                                               const int* __restrict__ rowF,
                                               const int* __restrict__ rowB,
                                               const unsigned int* __restrict__ pF,
                                               const unsigned int* __restrict__ pB,
                                               int n) {
    int i = blockIdx.x * 256 + threadIdx.x;
    if (i >= n * 9) return;
    size_t slb = (size_t)n * 72;
    int g = blockIdx.y;
    int row = i / 9, t = i - row * 9;
    int off = 8 * t;
    char* wp = zS + (size_t)g * slb + (size_t)row * 72 + off;
    float acc[4];
    ld4h(acc, wp);
    gath8(acc, zS + (size_t)(2 + g) * slb, off, rowF, pF, row);
    gath8(acc, zS + (size_t)(6 + g) * slb, off, rowB, pB, row);
#pragma unroll
    for (int k = 0; k < 4; ++k) acc[k] = 1.f / (1.f + expf(-acc[k]));
    st4h(acc, wp);
}

// hopAc: pass y in {0: cf1+=Tf*cf2, 1: cb1+=Tb*cb2}
__global__ __launch_bounds__(256) void hopAc_k(char* __restrict__ cS,
                                               const int* __restrict__ rowF,
                                               const int* __restrict__ rowB,
                                               const unsigned int* __restrict__ pF,
                                               const unsigned int* __restrict__ pB,
                                               int n) {
    int i = blockIdx.x * 256 + threadIdx.x;
    if (i >= n * 9) return;
    size_t slb = (size_t)n * 72;
    int pass = blockIdx.y;
    const int* rp = pass ? rowB : rowF;
    const unsigned int* pp = pass ? pB : pF;
    int dstS = pass ? 3 : 1;
    int srcS = pass ? 4 : 2;
    int row = i / 9, t = i - row * 9;
    int off = 8 * t;
    char* wp = cS + (size_t)dstS * slb + (size_t)row * 72 + off;
    float acc[4];
    ld4h(acc, wp);
    gath8(acc, cS + (size_t)srcS * slb, off, rp, pp, row);
    st4h(acc, wp);
}

// hopBc + GRU: h = z*h + (1-z)*tanh(cg + Tf*cf1 + Tb*cb1)
__global__ __launch_bounds__(256) void hopBcg_k(const char* __restrict__ cS,
                                                const char* __restrict__ zS,
                                                const int* __restrict__ rowF,
                                                const int* __restrict__ rowB,
                                                const unsigned int* __restrict__ pF,
                                                const unsigned int* __restrict__ pB,
                                                float* __restrict__ h, int n) {
    int i = blockIdx.x * 256 + threadIdx.x;
    if (i >= n * 9) return;
    size_t slb = (size_t)n * 72;
    int row = i / 9, t = i - row * 9;
    int off = 8 * t;
    float acc[4];
    ld4h(acc, cS + (size_t)row * 72 + off);              // cg
    gath8(acc, cS + slb, off, rowF, pF, row);            // + Tf*cf1
    gath8(acc, cS + 3 * slb, off, rowB, pB, row);        // + Tb*cb1
    float zv[4];
    ld4h(zv, zS + (size_t)row * 72 + off);               // z gate
    float* hp = h + (size_t)row * HS + 4 * t;
    float4 h4 = *(float4*)hp;
    float hv[4] = {h4.x, h4.y, h4.z, h4.w};
#pragma unroll
    for (int k = 0; k < 4; ++k) {
        float c = tanhf(acc[k]);
        hv[k] = zv[k] * hv[k] + (1.f - zv[k]) * c;
    }
    *(float4*)hp = make_float4(hv[0], hv[1], hv[2], hv[3]);
}

// ================= final =================

__global__ void final_k(const float* __restrict__ h, const float* __restrict__ Wl,
                        const float* __restrict__ bl, float* __restrict__ out, int n) {
    int i = blockIdx.x * blockDim.x + threadIdx.x;
    if (i < n) {
        float s = bl[0];
        const float* hr = h + (size_t)i * HS;
#pragma unroll
        for (int j = 0; j < NF; j++) s += hr[j] * Wl[j];
        out[i] = fmaxf(s, 0.f);
    }
}

// ================= launch =================

extern "C" void kernel_launch(void* const* d_in, const int* in_sizes, int n_in,
                              void* d_out, int out_size, void* d_ws, size_t ws_size,
                              hipStream_t stream) {
    const float* x   = (const float*)d_in[0];
    const int*   ei  = (const int*)d_in[1];
    const float* w   = (const float*)d_in[2];
    const float* tz  = (const float*)d_in[3];
    const float* bz  = (const float*)d_in[4];
    const float* tr_ = (const float*)d_in[5];
    const float* br  = (const float*)d_in[6];
    const float* tc  = (const float*)d_in[7];
    const float* bc  = (const float*)d_in[8];
    const float* Wl  = (const float*)d_in[9];
    const float* bl  = (const float*)d_in[10];

    const int n = in_sizes[0] / NF;   // 50000 (< 65536: packed 16-bit indices)
    const int E = in_sizes[2];        // 800000
    const int* src = ei;
    const int* dst = ei + E;

    float* out = (float*)d_out;       // [n]
    float* wf = out + n;              // [E]  = A[0]
    float* wb = wf + E;               // [E]  = A[1]

    char* p = (char*)d_ws;
    auto alloc = [&](size_t bytes) {
        char* r = p;
        p += (bytes + 15) & ~(size_t)15;
        return r;
    };
    int2* pairF = (int2*)alloc((size_t)E * 8);
    int2* pairB = (int2*)alloc((size_t)E * 8);
    unsigned int* pFp = (unsigned int*)alloc((size_t)E * 4);
    unsigned int* pBp = (unsigned int*)alloc((size_t)E * 4);
    int* rowF = (int*)alloc((size_t)(n + 1) * 4);
    int* rowB = (int*)alloc((size_t)(n + 1) * 4);
    unsigned int* cntF2 = (unsigned int*)alloc((size_t)((n + 1) / 2 + 4) * 4);
    unsigned int* cntB2 = (unsigned int*)alloc((size_t)((n + 1) / 2 + 4) * 4);
    float* deg_in  = (float*)alloc((size_t)n * 4);
    float* deg_out = (float*)alloc((size_t)n * 4);
    float* h  = (float*)alloc((size_t)n * HS * 4);
    char* zS  = alloc((size_t)n * 72 * 10);   // 10 z|r slabs
    char* cS  = alloc((size_t)n * 72 * 5);    // 5 c slabs
    float* PZ = (float*)alloc((size_t)71 * ZCOLS * 4);
    float* PC = (float*)alloc((size_t)71 * CCOLS * 4);
    // ranks live only during build: alias onto zS (6.4MB << 36MB)
    int* rankF = (int*)zS;
    int* rankB = rankF + E;

    const int gridE = (E + 255) / 256;
    const int gridN = (n + 255) / 256;
    const int g64 = (n + 63) / 64;
    const int g9 = (n * 9 + 255) / 256;
    const size_t cntBytes = ((size_t)((n + 1) / 2 + 4) * 4 + 15) & ~(size_t)15;

    // ---- CSR build ----
    hipMemsetAsync(cntF2, 0, 2 * cntBytes, stream);   // cntF2+cntB2 contiguous
    hipMemsetAsync(h, 0, (size_t)n * HS * sizeof(float), stream);
    degree2_k<<<gridE, 256, 0, stream>>>(src, dst, cntF2, cntB2, rankF, rankB, E);
    scan2_k<<<2, 1024, 0, stream>>>(cntF2, cntB2, rowF, rowB, n);
    scatter2_k<<<gridE, 256, 0, stream>>>(src, dst, w, rankF, rankB, rowF, rowB,
                                          pairF, pairB, E);
    segdeg_k<<<gridN, 256, 0, stream>>>(rowF, rowB, pairF, pairB, deg_in, deg_out, n);
    norm_k<<<gridE, 256, 0, stream>>>(src, dst, w, deg_out, deg_in, pairF, pairB,
                                      pFp, pBp, wf, wb, E);
    pack_k<<<(71 * (ZCOLS + CCOLS) + 255) / 256, 256, 0, stream>>>(tz, tr_, tc,
                                                                   bz, br, bc, PZ, PC);

    // ---- cell 1 (h == 0: K=35 GEMM) ----
    mm_z_k<1><<<g64, 512, 0, stream>>>(x, h, PZ, zS, n);
    hopAz_k<<<dim3(g9, 4), 256, 0, stream>>>(zS, rowF, rowB, pFp, pBp, n);
    hopBz_k<<<dim3(g9, 2), 256, 0, stream>>>(zS, rowF, rowB, pFp, pBp, n);
    mmc_k<<<g64, 512, 0, stream>>>(x, h, zS, PC, cS, n);
    hopAc_k<<<dim3(g9, 2), 256, 0, stream>>>(cS, rowF, rowB, pFp, pBp, n);
    hopBcg_k<<<g9, 256, 0, stream>>>(cS, zS, rowF, rowB, pFp, pBp, h, n);
    // ---- cell 2 ----
    mm_z_k<0><<<g64, 512, 0, stream>>>(x, h, PZ, zS, n);
    hopAz_k<<<dim3(g9, 4), 256, 0, stream>>>(zS, rowF, rowB, pFp, pBp, n);
    hopBz_k<<<dim3(g9, 2), 256, 0, stream>>>(zS, rowF, rowB, pFp, pBp, n);
    mmc_k<<<g64, 512, 0, stream>>>(x, h, zS, PC, cS, n);
    hopAc_k<<<dim3(g9, 2), 256, 0, stream>>>(cS, rowF, rowB, pFp, pBp, n);
    hopBcg_k<<<g9, 256, 0, stream>>>(cS, zS, rowF, rowB, pFp, pBp, h, n);

    final_k<<<gridN, 256, 0, stream>>>(h, Wl, bl, out, n);
}